// Round 13
// baseline (580.261 us; speedup 1.0000x reference)
//
#include <hip/hip_runtime.h>
#include <math.h>

#define B_    8192
#define K_    64
#define C_    64
#define FEAT_ 172
#define TDIM_ 100
#define TOKH_ 32
#define CHH_  256
#define G_    100
#define L_    2
#define CAT_  236      // C_+FEAT_

typedef _Float16 f16x8 __attribute__((ext_vector_type(8)));
typedef _Float16 f16x4 __attribute__((ext_vector_type(4)));
typedef __fp16   h16x2 __attribute__((ext_vector_type(2)));   // cvt_pkrtz native type
typedef float    f32x4 __attribute__((ext_vector_type(4)));

// Packed f32->f16 conversions (v_cvt_pkrtz_f16_f32: 2 elems/inst, RTZ).
// The builtin returns __fp16x2; lanes are bit-identical to _Float16.
__device__ __forceinline__ f16x4 pk4(float a, float b, float c, float d) {
    const h16x2 lo = __builtin_amdgcn_cvt_pkrtz(a, b);
    const h16x2 hi = __builtin_amdgcn_cvt_pkrtz(c, d);
    f16x4 r;
    r[0] = (_Float16)lo[0]; r[1] = (_Float16)lo[1];
    r[2] = (_Float16)hi[0]; r[3] = (_Float16)hi[1];
    return r;
}
__device__ __forceinline__ f16x8 pk8v(const float* v) {
    const h16x2 p0 = __builtin_amdgcn_cvt_pkrtz(v[0], v[1]);
    const h16x2 p1 = __builtin_amdgcn_cvt_pkrtz(v[2], v[3]);
    const h16x2 p2 = __builtin_amdgcn_cvt_pkrtz(v[4], v[5]);
    const h16x2 p3 = __builtin_amdgcn_cvt_pkrtz(v[6], v[7]);
    f16x8 r;
    r[0]=(_Float16)p0[0]; r[1]=(_Float16)p0[1];
    r[2]=(_Float16)p1[0]; r[3]=(_Float16)p1[1];
    r[4]=(_Float16)p2[0]; r[5]=(_Float16)p2[1];
    r[6]=(_Float16)p3[0]; r[7]=(_Float16)p3[1];
    return r;
}

// Fast exact-range cos: f32 product (same rounding as the jax ref), f64 range
// reduction (exact for |p|<=2e6), hardware v_cos (takes revolutions).
__device__ __forceinline__ float fast_cos(float p) {
    const double rev = (double)p * 0.15915494309189535;   // p / 2pi
    const double fr  = rev - __builtin_rint(rev);         // [-0.5, 0.5]
#if __has_builtin(__builtin_amdgcn_cosf)
    return __builtin_amdgcn_cosf((float)fr);
#else
    return __cosf(6.283185307179586f * (float)fr);
#endif
}

// GELU via A&S 7.1.25 erf (|err|<2.5e-5), v_rcp instead of fdiv: ~13 VALU.
__device__ __forceinline__ float gelu_f(float x) {
    const float z  = x * 0.70710678118654752f;
    const float az = fabsf(z);
    const float t  = __builtin_amdgcn_rcpf(fmaf(0.47047f, az, 1.0f));
    const float poly = t * (0.3480242f + t * (-0.0958798f + t * 0.7478556f));
    const float e  = __expf(-az * az);
    float erfv = fmaf(-poly, e, 1.0f);
    erfv = copysignf(erfv, z);
    return 0.5f * x * (1.0f + erfv);
}

// f16 state RMW: p += add (f32 math, f16 storage, packed cvt)
__device__ __forceinline__ void rmw16(_Float16* p, f32x4 add) {
    const f16x4 old = *(const f16x4*)p;
    *(f16x4*)p = pk4((float)old[0] + add[0], (float)old[1] + add[1],
                     (float)old[2] + add[2], (float)old[3] + add[3]);
}

// ---------------------------------------------------------------------------
// Prepack weights to f16. pW (64 x 288): cols 0..171 edge, 176..275 time.
// pOW (176 x 256): pOW[n][k] = out_W[k][n], zero-padded.
// ---------------------------------------------------------------------------
__global__ __launch_bounds__(256)
void prepack_kernel(const float* __restrict__ proj_W,
                    const float* __restrict__ tW1, const float* __restrict__ tW2,
                    const float* __restrict__ cW1, const float* __restrict__ cW2,
                    const float* __restrict__ out_W,
                    _Float16* __restrict__ pW,
                    _Float16* __restrict__ pT1, _Float16* __restrict__ pT2,
                    _Float16* __restrict__ pC1, _Float16* __restrict__ pC2,
                    _Float16* __restrict__ pOW) {
    const int stride = gridDim.x * blockDim.x;
    const int t0 = blockIdx.x * blockDim.x + threadIdx.x;
    for (int i = t0; i < 64 * 288; i += stride) {
        const int c = i / 288, ii = i % 288;
        float v = 0.f;
        if (ii < 172) v = proj_W[ii * 64 + c];
        else if (ii >= 176 && ii < 276) v = proj_W[(ii - 4) * 64 + c];
        pW[i] = (_Float16)v;
    }
    for (int i = t0; i < 2 * 32 * 64; i += stride) {           // pT1[l][j][k]
        const int l = i / 2048, rem = i % 2048, j = rem / 64, k = rem % 64;
        pT1[i] = (_Float16)tW1[l * 2048 + k * 32 + j];
    }
    for (int i = t0; i < 2 * 64 * 32; i += stride) {           // pT2[l][k][j]
        const int l = i / 2048, rem = i % 2048, k = rem / 32, j = rem % 32;
        pT2[i] = (_Float16)tW2[l * 2048 + j * 64 + k];
    }
    for (int i = t0; i < 2 * 256 * 64; i += stride) {          // pC1[l][n][c]
        const int l = i / 16384, rem = i % 16384, n = rem / 64, c = rem % 64;
        pC1[i] = (_Float16)cW1[l * 16384 + c * 256 + n];
    }
    for (int i = t0; i < 2 * 64 * 256; i += stride) {          // pC2[l][c][n]
        const int l = i / 16384, rem = i % 16384, c = rem / 256, n = rem % 256;
        pC2[i] = (_Float16)cW2[l * 16384 + n * 64 + c];
    }
    for (int i = t0; i < 176 * 256; i += stride) {             // pOW[n][k]
        const int n = i / 256, k = i % 256;
        pOW[i] = (n < FEAT_ && k < CAT_) ? (_Float16)out_W[k * FEAT_ + n]
                                         : (_Float16)0.f;
    }
}

// ---------------------------------------------------------------------------
// Fused kernel, 2 batch elements/block (round-11 verified structure: f16 xf
// state, dual sh, shared weight frags, (256,4), 4 blocks/CU). Round-12: all
// f32->f16 conversions packed via v_cvt_pkrtz.
// Frag maps (HW-verified): A/B: lane l -> row/col l&15, kelem 8*(l>>4)+i;
// D: col l&15, row 4*(l>>4)+jj.
// ---------------------------------------------------------------------------
__global__ __launch_bounds__(256, 4)
void fused_kernel(const float* __restrict__ edge_table,
                  const float* __restrict__ time_w,
                  const _Float16* __restrict__ pW,
                  const float* __restrict__ proj_b,
                  const int*   __restrict__ nbr_nids,
                  const int*   __restrict__ nbr_eids,
                  const float* __restrict__ node_times,
                  const float* __restrict__ nbr_times,
                  const float* __restrict__ tok_ln_s, const float* __restrict__ tok_ln_b,
                  const float* __restrict__ tok_b1,   const float* __restrict__ tok_b2,
                  const float* __restrict__ ch_ln_s,  const float* __restrict__ ch_ln_b,
                  const float* __restrict__ ch_b1,    const float* __restrict__ ch_b2,
                  const _Float16* __restrict__ pT1, const _Float16* __restrict__ pT2,
                  const _Float16* __restrict__ pC1, const _Float16* __restrict__ pC2,
                  float* __restrict__ agg_out) {
    __shared__ __attribute__((aligned(16))) _Float16 xf[2][64 * 72];  // 18432 B
    __shared__ __attribute__((aligned(16))) _Float16 sh[2][64 * 72];  // 18432 B

    const int bid  = blockIdx.x;
    const int t    = threadIdx.x;
    const int lane = t & 63;
    const int w    = t >> 6;
    const int r    = lane & 15;
    const int g    = lane >> 4;
    const int row16 = 16 * w + r;

    // ================= proj phase =================
    {
        const float* erow[2];
        bool  nz[2];
        float dt[2];
#pragma unroll
        for (int bb = 0; bb < 2; ++bb) {
            const size_t bgl = (size_t)(2 * bid + bb) * K_ + row16;
            erow[bb] = edge_table + (size_t)nbr_eids[bgl] * FEAT_;
            nz[bb]   = (nbr_nids[bgl] == 0);
            dt[bb]   = node_times[2 * bid + bb] - nbr_times[bgl];
        }

        f32x4 pacc[2][4];
#pragma unroll
        for (int nt = 0; nt < 4; ++nt) {
            const f32x4 pb = *(const f32x4*)&proj_b[16 * nt + 4 * g];
            pacc[0][nt] = pb; pacc[1][nt] = pb;
        }

        const int c0b = 8 * g;
#pragma unroll
        for (int kk = 0; kk < 9; ++kk) {
            const int c0 = 32 * kk + c0b;
            f16x8 af[4];
#pragma unroll
            for (int nt = 0; nt < 4; ++nt)
                af[nt] = *(const f16x8*)&pW[(16 * nt + r) * 288 + c0];
            f16x8 bf[2];
#pragma unroll
            for (int bb = 0; bb < 2; ++bb) {
                float ev[8];
                if (c0 + 8 <= FEAT_) {
                    const float4 v0 = *(const float4*)(erow[bb] + c0);
                    const float4 v1 = *(const float4*)(erow[bb] + c0 + 4);
                    ev[0]=v0.x; ev[1]=v0.y; ev[2]=v0.z; ev[3]=v0.w;
                    ev[4]=v1.x; ev[5]=v1.y; ev[6]=v1.z; ev[7]=v1.w;
                } else if (c0 < 176) {       // c0==168: edge 168..171 + pad
                    const float4 v0 = *(const float4*)(erow[bb] + 168);
                    ev[0]=v0.x; ev[1]=v0.y; ev[2]=v0.z; ev[3]=v0.w;
                    ev[4]=0.f; ev[5]=0.f; ev[6]=0.f; ev[7]=0.f;
                } else {                     // time cols
                    const int d0 = c0 - 176;
#pragma unroll
                    for (int i = 0; i < 8; ++i) {
                        const int d = d0 + i;
                        float tv = 0.f;
                        if (d < TDIM_) tv = fast_cos(dt[bb] * time_w[d]);
                        ev[i] = nz[bb] ? 0.f : tv;
                    }
                }
                bf[bb] = pk8v(ev);
            }
#pragma unroll
            for (int nt = 0; nt < 4; ++nt) {
                pacc[0][nt] = __builtin_amdgcn_mfma_f32_16x16x32_f16(af[nt], bf[0], pacc[0][nt], 0, 0, 0);
                pacc[1][nt] = __builtin_amdgcn_mfma_f32_16x16x32_f16(af[nt], bf[1], pacc[1][nt], 0, 0, 0);
            }
        }
#pragma unroll
        for (int bb = 0; bb < 2; ++bb)
#pragma unroll
            for (int nt = 0; nt < 4; ++nt)
                *(f16x4*)&xf[bb][row16 * 72 + 16 * nt + 4 * g] =
                    pk4(pacc[bb][nt][0], pacc[bb][nt][1], pacc[bb][nt][2], pacc[bb][nt][3]);
    }
    __syncthreads();

    // ================= mixer layers =================
    for (int l = 0; l < L_; ++l) {
        // ---- token LN (over k, per c), both b ----
#pragma unroll
        for (int bb = 0; bb < 2; ++bb) {
            const int c0 = row16;
            float xv[16], s = 0.f, ss = 0.f;
#pragma unroll
            for (int u = 0; u < 16; ++u) {
                const float v = (float)xf[bb][(16 * g + u) * 72 + c0];
                xv[u] = v; s += v; ss += v * v;
            }
            s += __shfl_xor(s, 16); ss += __shfl_xor(ss, 16);
            s += __shfl_xor(s, 32); ss += __shfl_xor(ss, 32);
            const float mean = s * 0.015625f;
            const float rstd = rsqrtf(ss * 0.015625f - mean * mean + 1e-5f);
            const float* tls = tok_ln_s + l * 64 + 16 * g;
            const float* tlb = tok_ln_b + l * 64 + 16 * g;
            float hv[16];
#pragma unroll
            for (int u = 0; u < 16; ++u)
                hv[u] = (xv[u] - mean) * rstd * tls[u] + tlb[u];
            *(f16x8*)&sh[bb][c0 * 72 + 16 * g]     = pk8v(hv);       // xh^T[c][k]
            *(f16x8*)&sh[bb][c0 * 72 + 16 * g + 8] = pk8v(hv + 8);
        }
        // ---- token G1 + G2 + residual (weight frags shared across b) ----
        {
            const _Float16* W1 = pT1 + l * 2048;   // [j][k]
            const _Float16* W2 = pT2 + l * 2048;   // [k][j]
            f16x8 tb0[2], tb1[2];
#pragma unroll
            for (int bb = 0; bb < 2; ++bb) {
                tb0[bb] = *(const f16x8*)&sh[bb][row16 * 72 + 8 * g];
                tb1[bb] = *(const f16x8*)&sh[bb][row16 * 72 + 32 + 8 * g];
            }
#pragma unroll
            for (int nt = 0; nt < 2; ++nt) {
                const f16x8 a0 = *(const f16x8*)&W1[(16 * nt + r) * 64 + 8 * g];
                const f16x8 a1 = *(const f16x8*)&W1[(16 * nt + r) * 64 + 32 + 8 * g];
                const f32x4 bias = *(const f32x4*)&tok_b1[l * 32 + 16 * nt + 4 * g];
#pragma unroll
                for (int bb = 0; bb < 2; ++bb) {
                    f32x4 acc = bias;
                    acc = __builtin_amdgcn_mfma_f32_16x16x32_f16(a0, tb0[bb], acc, 0, 0, 0);
                    acc = __builtin_amdgcn_mfma_f32_16x16x32_f16(a1, tb1[bb], acc, 0, 0, 0);
                    *(f16x4*)&sh[bb][row16 * 72 + 16 * nt + 4 * g] =
                        pk4(gelu_f(acc[0]), gelu_f(acc[1]), gelu_f(acc[2]), gelu_f(acc[3]));
                }
            }
            f16x8 a[2];
#pragma unroll
            for (int bb = 0; bb < 2; ++bb)
                a[bb] = *(const f16x8*)&sh[bb][row16 * 72 + 8 * g];   // H: c=row16
#pragma unroll
            for (int nt = 0; nt < 4; ++nt) {
                const int kcol = 16 * nt + r;
                const float bk = tok_b2[l * 64 + kcol];
                const f16x8 bf = *(const f16x8*)&W2[kcol * 32 + 8 * g];
#pragma unroll
                for (int bb = 0; bb < 2; ++bb) {
                    f32x4 acc = {bk, bk, bk, bk};
                    acc = __builtin_amdgcn_mfma_f32_16x16x32_f16(a[bb], bf, acc, 0, 0, 0);
                    rmw16(&xf[bb][kcol * 72 + 16 * w + 4 * g], acc);   // own c-slice
                }
            }
        }
        __syncthreads();   // token residual visible before channel LN

        // ---- channel LN (over c, per k), both b ----
#pragma unroll
        for (int bb = 0; bb < 2; ++bb) {
            const int k0 = row16;
            const f16x8 cva = *(const f16x8*)&xf[bb][k0 * 72 + 16 * g];
            const f16x8 cvb = *(const f16x8*)&xf[bb][k0 * 72 + 16 * g + 8];
            float cv[16], s = 0.f, ss = 0.f;
#pragma unroll
            for (int e = 0; e < 8; ++e) { cv[e] = (float)cva[e]; cv[8 + e] = (float)cvb[e]; }
#pragma unroll
            for (int e = 0; e < 16; ++e) { s += cv[e]; ss += cv[e] * cv[e]; }
            s += __shfl_xor(s, 16); ss += __shfl_xor(ss, 16);
            s += __shfl_xor(s, 32); ss += __shfl_xor(ss, 32);
            const float mean = s * 0.015625f;
            const float rstd = rsqrtf(ss * 0.015625f - mean * mean + 1e-5f);
            const float* cls = ch_ln_s + l * 64 + 16 * g;
            const float* clb = ch_ln_b + l * 64 + 16 * g;
            float hv[16];
#pragma unroll
            for (int e = 0; e < 16; ++e)
                hv[e] = (cv[e] - mean) * rstd * cls[e] + clb[e];
            *(f16x8*)&sh[bb][k0 * 72 + 16 * g]     = pk8v(hv);       // xh[k][c]
            *(f16x8*)&sh[bb][k0 * 72 + 16 * g + 8] = pk8v(hv + 8);
        }
        // ---- channel MLP (shared Wc1/Wc2 frags; q unrolled) ----
        {
            f16x8 ca0[2], ca1[2];
#pragma unroll
            for (int bb = 0; bb < 2; ++bb) {
                ca0[bb] = *(const f16x8*)&sh[bb][row16 * 72 + 8 * g];
                ca1[bb] = *(const f16x8*)&sh[bb][row16 * 72 + 32 + 8 * g];
            }
            const _Float16* Wc1 = pC1 + l * 16384;   // [n][c]
            const _Float16* Wc2 = pC2 + l * 16384;   // [c][n]
            f32x4 cacc[2][4];
#pragma unroll
            for (int nt = 0; nt < 4; ++nt) {
                const f32x4 cb = *(const f32x4*)&ch_b2[l * 64 + 16 * nt + 4 * g];
                cacc[0][nt] = cb; cacc[1][nt] = cb;
            }
#pragma unroll
            for (int q = 0; q < 4; ++q) {
#pragma unroll
                for (int nt = 0; nt < 4; ++nt) {
                    const int nrow = 64 * q + 16 * nt + r;
                    const f16x8 a0 = *(const f16x8*)&Wc1[nrow * 64 + 8 * g];
                    const f16x8 a1 = *(const f16x8*)&Wc1[nrow * 64 + 32 + 8 * g];
                    const f32x4 hb1 = *(const f32x4*)&ch_b1[l * 256 + 64 * q + 16 * nt + 4 * g];
#pragma unroll
                    for (int bb = 0; bb < 2; ++bb) {
                        f32x4 acc = hb1;
                        acc = __builtin_amdgcn_mfma_f32_16x16x32_f16(a0, ca0[bb], acc, 0, 0, 0);
                        acc = __builtin_amdgcn_mfma_f32_16x16x32_f16(a1, ca1[bb], acc, 0, 0, 0);
                        *(f16x4*)&sh[bb][row16 * 72 + 16 * nt + 4 * g] =
                            pk4(gelu_f(acc[0]), gelu_f(acc[1]), gelu_f(acc[2]), gelu_f(acc[3]));
                    }
                }
#pragma unroll
                for (int ks = 0; ks < 2; ++ks) {
                    f16x8 bh[2];
#pragma unroll
                    for (int bb = 0; bb < 2; ++bb)
                        bh[bb] = *(const f16x8*)&sh[bb][row16 * 72 + 32 * ks + 8 * g];
#pragma unroll
                    for (int nt2 = 0; nt2 < 4; ++nt2) {
                        const f16x8 a2 = *(const f16x8*)&Wc2[(16 * nt2 + r) * 256 + 64 * q + 32 * ks + 8 * g];
                        cacc[0][nt2] = __builtin_amdgcn_mfma_f32_16x16x32_f16(a2, bh[0], cacc[0][nt2], 0, 0, 0);
                        cacc[1][nt2] = __builtin_amdgcn_mfma_f32_16x16x32_f16(a2, bh[1], cacc[1][nt2], 0, 0, 0);
                    }
                }
            }
#pragma unroll
            for (int bb = 0; bb < 2; ++bb)
#pragma unroll
                for (int nt2 = 0; nt2 < 4; ++nt2)
                    rmw16(&xf[bb][row16 * 72 + 16 * nt2 + 4 * g], cacc[bb][nt2]);
        }
        __syncthreads();   // layer complete
    }

    // ---- agg: mean over k per c, both b ----
#pragma unroll
    for (int bb = 0; bb < 2; ++bb) {
        float ssum = 0.f;
#pragma unroll
        for (int u = 0; u < 16; ++u) ssum += (float)xf[bb][(16 * g + u) * 72 + row16];
        ssum += __shfl_xor(ssum, 16);
        ssum += __shfl_xor(ssum, 32);
        if (g == 0) agg_out[(size_t)(2 * bid + bb) * 64 + row16] = ssum * 0.015625f;
    }
}

// ---------------------------------------------------------------------------
// Kernel 3: 16 batch rows per block, 512 threads. Gap gather split into two
// 50-id halves per b (sub = 0/1) to halve the serial latency chain; partials
// combined via LDS. MFMA GEMV phase uses all 8 waves.
// ---------------------------------------------------------------------------
__global__ __launch_bounds__(512)
void out_kernel(const float* __restrict__ node_table,
                const float* __restrict__ agg,
                const _Float16* __restrict__ pOW,
                const float* __restrict__ out_b,
                const int*   __restrict__ node_ids,
                const int*   __restrict__ gap_ids,
                float* __restrict__ out) {
    __shared__ __attribute__((aligned(16))) _Float16 inb16[16][264];
    __shared__ float part[16][176];
    __shared__ int   nv1[16];
    const int t     = threadIdx.x;
    const int bbase = blockIdx.x * 16;
    const int m     = t >> 5;          // local b row 0..15
    const int sub   = (t >> 4) & 1;    // id-half
    const int c16   = t & 15;
    const int b     = bbase + m;

    if (sub == 0) {
#pragma unroll
        for (int j = 0; j < 4; ++j)
            inb16[m][c16 + 16 * j] = (_Float16)agg[(size_t)b * C_ + c16 + 16 * j];
        inb16[m][236 + c16] = (_Float16)0.f;            // 236..251
        if (c16 < 12) inb16[m][252 + c16] = (_Float16)0.f;  // 252..263
    }
    // gather: this sub's 50 ids
    float acc[11];
#pragma unroll
    for (int j = 0; j < 11; ++j) acc[j] = 0.f;
    int nv = 0;
    {
        const int* gid = gap_ids + (size_t)b * G_ + 50 * sub;
        for (int gg = 0; gg < 50; ++gg) {
            const int id = gid[gg];
            if (id > 0) {
                ++nv;
                const float* row = node_table + (size_t)id * FEAT_;
#pragma unroll
                for (int j = 0; j < 11; ++j) {
                    const int c = c16 + 16 * j;
                    if (c < FEAT_) acc[j] += row[c];
                }
            }
        }
    }
    if (sub == 1) {
#pragma unroll
        for (int j = 0; j < 11; ++j) {
            const int c = c16 + 16 * j;
            if (c < FEAT_) part[m][c] = acc[j];
        }
        if (c16 == 0) nv1[m] = nv;
    }
    __syncthreads();
    if (sub == 0) {
        const int nvt = nv + nv1[m];
        const float scale = 1.0f / (float)(G_ * (nvt > 0 ? nvt : 1));
        const float* nrow = node_table + (size_t)node_ids[b] * FEAT_;
#pragma unroll
        for (int j = 0; j < 11; ++j) {
            const int c = c16 + 16 * j;
            if (c < FEAT_)
                inb16[m][64 + c] = (_Float16)(fmaf(acc[j] + part[m][c], scale, nrow[c]));
        }
    }
    __syncthreads();

    // MFMA GEMV: 11 n-tiles over 8 waves
    const int lane = t & 63;
    const int w = t >> 6;
    const int r = lane & 15;
    const int g = lane >> 4;
    f16x8 bf[8];
#pragma unroll
    for (int kk = 0; kk < 8; ++kk)
        bf[kk] = *(const f16x8*)&inb16[r][32 * kk + 8 * g];
    for (int nt = w; nt < 11; nt += 8) {
        const int n0 = nt * 16 + 4 * g;
        const int bidx = (n0 + 4 <= FEAT_) ? n0 : (FEAT_ - 4);
        f32x4 acc = *(const f32x4*)&out_b[bidx];
#pragma unroll
        for (int kk = 0; kk < 8; ++kk) {
            const f16x8 af = *(const f16x8*)&pOW[(nt * 16 + r) * 256 + 32 * kk + 8 * g];
            acc = __builtin_amdgcn_mfma_f32_16x16x32_f16(af, bf[kk], acc, 0, 0, 0);
        }
        if (n0 + 4 <= FEAT_)
            *(f32x4*)&out[(size_t)(bbase + r) * FEAT_ + n0] = acc;
    }
}

// ---------------------------------------------------------------------------
extern "C" void kernel_launch(void* const* d_in, const int* in_sizes, int n_in,
                              void* d_out, int out_size, void* d_ws, size_t ws_size,
                              hipStream_t stream) {
    const float* node_table = (const float*)d_in[0];
    const float* edge_table = (const float*)d_in[1];
    const float* time_w     = (const float*)d_in[2];
    const float* proj_W     = (const float*)d_in[3];
    const float* proj_b     = (const float*)d_in[4];
    const float* tok_ln_s   = (const float*)d_in[5];
    const float* tok_ln_b   = (const float*)d_in[6];
    const float* tok_W1     = (const float*)d_in[7];
    const float* tok_b1     = (const float*)d_in[8];
    const float* tok_W2     = (const float*)d_in[9];
    const float* tok_b2     = (const float*)d_in[10];
    const float* ch_ln_s    = (const float*)d_in[11];
    const float* ch_ln_b    = (const float*)d_in[12];
    const float* ch_W1      = (const float*)d_in[13];
    const float* ch_b1      = (const float*)d_in[14];
    const float* ch_W2      = (const float*)d_in[15];
    const float* ch_b2      = (const float*)d_in[16];
    const float* out_W      = (const float*)d_in[17];
    const float* out_b      = (const float*)d_in[18];
    const int*   node_ids   = (const int*)d_in[19];
    const int*   nbr_nids   = (const int*)d_in[20];
    const int*   nbr_eids   = (const int*)d_in[21];
    const int*   gap_ids    = (const int*)d_in[22];
    const float* node_times = (const float*)d_in[23];
    const float* nbr_times  = (const float*)d_in[24];

    float* agg_buf = (float*)d_ws;                       // B*C f32 = 2 MiB
    _Float16* pw   = (_Float16*)(agg_buf + (size_t)B_ * C_);
    _Float16* pW   = pw;               // 64*288   = 18432
    _Float16* pT1  = pW  + 18432;      // 2*32*64  = 4096
    _Float16* pT2  = pT1 + 4096;       // 2*64*32  = 4096
    _Float16* pC1  = pT2 + 4096;       // 2*256*64 = 32768
    _Float16* pC2  = pC1 + 32768;      // 2*64*256 = 32768
    _Float16* pOW  = pC2 + 32768;      // 176*256  = 45056
    float* outp    = (float*)d_out;

    prepack_kernel<<<64, 256, 0, stream>>>(proj_W, tok_W1, tok_W2, ch_W1, ch_W2,
                                           out_W, pW, pT1, pT2, pC1, pC2, pOW);
    fused_kernel<<<B_ / 2, 256, 0, stream>>>(edge_table, time_w, pW, proj_b,
                                             nbr_nids, nbr_eids, node_times, nbr_times,
                                             tok_ln_s, tok_ln_b, tok_b1, tok_b2,
                                             ch_ln_s, ch_ln_b, ch_b1, ch_b2,
                                             pT1, pT2, pC1, pC2,
                                             agg_buf);
    out_kernel<<<B_ / 16, 512, 0, stream>>>(node_table, agg_buf, pOW, out_b,
                                            node_ids, gap_ids, outp);
}

// Round 14
// 509.983 us; speedup vs baseline: 1.1378x; 1.1378x over previous
//
#include <hip/hip_runtime.h>
#include <math.h>

#define B_    8192
#define K_    64
#define C_    64
#define FEAT_ 172
#define TDIM_ 100
#define TOKH_ 32
#define CHH_  256
#define G_    100
#define L_    2
#define CAT_  236      // C_+FEAT_

typedef _Float16 f16x8 __attribute__((ext_vector_type(8)));
typedef _Float16 f16x4 __attribute__((ext_vector_type(4)));
typedef float    f32x4 __attribute__((ext_vector_type(4)));

// Fast exact-range cos: f32 product (same rounding as the jax ref), f64 range
// reduction (exact for |p|<=2e6), hardware v_cos (takes revolutions).
__device__ __forceinline__ float fast_cos(float p) {
    const double rev = (double)p * 0.15915494309189535;   // p / 2pi
    const double fr  = rev - __builtin_rint(rev);         // [-0.5, 0.5]
#if __has_builtin(__builtin_amdgcn_cosf)
    return __builtin_amdgcn_cosf((float)fr);
#else
    return __cosf(6.283185307179586f * (float)fr);
#endif
}

// GELU via A&S 7.1.25 erf (|err|<2.5e-5), v_rcp instead of fdiv: ~13 VALU.
__device__ __forceinline__ float gelu_f(float x) {
    const float z  = x * 0.70710678118654752f;
    const float az = fabsf(z);
    const float t  = __builtin_amdgcn_rcpf(fmaf(0.47047f, az, 1.0f));
    const float poly = t * (0.3480242f + t * (-0.0958798f + t * 0.7478556f));
    const float e  = __expf(-az * az);
    float erfv = fmaf(-poly, e, 1.0f);
    erfv = copysignf(erfv, z);
    return 0.5f * x * (1.0f + erfv);
}

// f16 state RMW: p += add (f32 math, f16 storage)
__device__ __forceinline__ void rmw16(_Float16* p, f32x4 add) {
    const f16x4 old = *(const f16x4*)p;
    f16x4 nw;
#pragma unroll
    for (int j = 0; j < 4; ++j) nw[j] = (_Float16)((float)old[j] + add[j]);
    *(f16x4*)p = nw;
}

// ---------------------------------------------------------------------------
// Prepack weights to f16. pW (64 x 288): cols 0..171 edge, 176..275 time.
// pOW (176 x 256): pOW[n][k] = out_W[k][n], zero-padded.
// ---------------------------------------------------------------------------
__global__ __launch_bounds__(256)
void prepack_kernel(const float* __restrict__ proj_W,
                    const float* __restrict__ tW1, const float* __restrict__ tW2,
                    const float* __restrict__ cW1, const float* __restrict__ cW2,
                    const float* __restrict__ out_W,
                    _Float16* __restrict__ pW,
                    _Float16* __restrict__ pT1, _Float16* __restrict__ pT2,
                    _Float16* __restrict__ pC1, _Float16* __restrict__ pC2,
                    _Float16* __restrict__ pOW) {
    const int stride = gridDim.x * blockDim.x;
    const int t0 = blockIdx.x * blockDim.x + threadIdx.x;
    for (int i = t0; i < 64 * 288; i += stride) {
        const int c = i / 288, ii = i % 288;
        float v = 0.f;
        if (ii < 172) v = proj_W[ii * 64 + c];
        else if (ii >= 176 && ii < 276) v = proj_W[(ii - 4) * 64 + c];
        pW[i] = (_Float16)v;
    }
    for (int i = t0; i < 2 * 32 * 64; i += stride) {           // pT1[l][j][k]
        const int l = i / 2048, rem = i % 2048, j = rem / 64, k = rem % 64;
        pT1[i] = (_Float16)tW1[l * 2048 + k * 32 + j];
    }
    for (int i = t0; i < 2 * 64 * 32; i += stride) {           // pT2[l][k][j]
        const int l = i / 2048, rem = i % 2048, k = rem / 32, j = rem % 32;
        pT2[i] = (_Float16)tW2[l * 2048 + j * 64 + k];
    }
    for (int i = t0; i < 2 * 256 * 64; i += stride) {          // pC1[l][n][c]
        const int l = i / 16384, rem = i % 16384, n = rem / 64, c = rem % 64;
        pC1[i] = (_Float16)cW1[l * 16384 + c * 256 + n];
    }
    for (int i = t0; i < 2 * 64 * 256; i += stride) {          // pC2[l][c][n]
        const int l = i / 16384, rem = i % 16384, c = rem / 256, n = rem % 256;
        pC2[i] = (_Float16)cW2[l * 16384 + n * 64 + c];
    }
    for (int i = t0; i < 176 * 256; i += stride) {             // pOW[n][k]
        const int n = i / 256, k = i % 256;
        pOW[i] = (n < FEAT_ && k < CAT_) ? (_Float16)out_W[k * FEAT_ + n]
                                         : (_Float16)0.f;
    }
}

// ---------------------------------------------------------------------------
// Fused kernel — EXACT round-11 verified version (486 us, absmax 0.0156):
// 2 batch elements/block, f16 xf state (f32 math in regs), dual sh buffers,
// shared weight frags (1 load -> 2 MFMAs), (256,4) -> 4 blocks/CU.
// Scalar f16 casts (packed-cvt attempts r12/r13 regressed: pointer-arg
// arrays spilled to scratch, rule #20).
// Frag maps (HW-verified): A/B: lane l -> row/col l&15, kelem 8*(l>>4)+i;
// D: col l&15, row 4*(l>>4)+jj.
// ---------------------------------------------------------------------------
__global__ __launch_bounds__(256, 4)
void fused_kernel(const float* __restrict__ edge_table,
                  const float* __restrict__ time_w,
                  const _Float16* __restrict__ pW,
                  const float* __restrict__ proj_b,
                  const int*   __restrict__ nbr_nids,
                  const int*   __restrict__ nbr_eids,
                  const float* __restrict__ node_times,
                  const float* __restrict__ nbr_times,
                  const float* __restrict__ tok_ln_s, const float* __restrict__ tok_ln_b,
                  const float* __restrict__ tok_b1,   const float* __restrict__ tok_b2,
                  const float* __restrict__ ch_ln_s,  const float* __restrict__ ch_ln_b,
                  const float* __restrict__ ch_b1,    const float* __restrict__ ch_b2,
                  const _Float16* __restrict__ pT1, const _Float16* __restrict__ pT2,
                  const _Float16* __restrict__ pC1, const _Float16* __restrict__ pC2,
                  float* __restrict__ agg_out) {
    __shared__ __attribute__((aligned(16))) _Float16 xf[2][64 * 72];  // 18432 B
    __shared__ __attribute__((aligned(16))) _Float16 sh[2][64 * 72];  // 18432 B

    const int bid  = blockIdx.x;
    const int t    = threadIdx.x;
    const int lane = t & 63;
    const int w    = t >> 6;
    const int r    = lane & 15;
    const int g    = lane >> 4;
    const int row16 = 16 * w + r;

    // ================= proj phase =================
    {
        const float* erow[2];
        bool  nz[2];
        float dt[2];
#pragma unroll
        for (int bb = 0; bb < 2; ++bb) {
            const size_t bgl = (size_t)(2 * bid + bb) * K_ + row16;
            erow[bb] = edge_table + (size_t)nbr_eids[bgl] * FEAT_;
            nz[bb]   = (nbr_nids[bgl] == 0);
            dt[bb]   = node_times[2 * bid + bb] - nbr_times[bgl];
        }

        f32x4 pacc[2][4];
#pragma unroll
        for (int nt = 0; nt < 4; ++nt) {
            const f32x4 pb = *(const f32x4*)&proj_b[16 * nt + 4 * g];
            pacc[0][nt] = pb; pacc[1][nt] = pb;
        }

        const int c0b = 8 * g;
#pragma unroll
        for (int kk = 0; kk < 9; ++kk) {
            const int c0 = 32 * kk + c0b;
            f16x8 af[4];
#pragma unroll
            for (int nt = 0; nt < 4; ++nt)
                af[nt] = *(const f16x8*)&pW[(16 * nt + r) * 288 + c0];
            f16x8 bf[2];
#pragma unroll
            for (int bb = 0; bb < 2; ++bb) {
                if (c0 + 8 <= FEAT_) {
                    const float4 v0 = *(const float4*)(erow[bb] + c0);
                    const float4 v1 = *(const float4*)(erow[bb] + c0 + 4);
                    bf[bb][0]=(_Float16)v0.x; bf[bb][1]=(_Float16)v0.y;
                    bf[bb][2]=(_Float16)v0.z; bf[bb][3]=(_Float16)v0.w;
                    bf[bb][4]=(_Float16)v1.x; bf[bb][5]=(_Float16)v1.y;
                    bf[bb][6]=(_Float16)v1.z; bf[bb][7]=(_Float16)v1.w;
                } else if (c0 < 176) {       // c0==168: edge 168..171 + pad
                    const float4 v0 = *(const float4*)(erow[bb] + 168);
                    bf[bb][0]=(_Float16)v0.x; bf[bb][1]=(_Float16)v0.y;
                    bf[bb][2]=(_Float16)v0.z; bf[bb][3]=(_Float16)v0.w;
                    bf[bb][4]=(_Float16)0.f; bf[bb][5]=(_Float16)0.f;
                    bf[bb][6]=(_Float16)0.f; bf[bb][7]=(_Float16)0.f;
                } else {                     // time cols
                    const int d0 = c0 - 176;
#pragma unroll
                    for (int i = 0; i < 8; ++i) {
                        const int d = d0 + i;
                        float tv = 0.f;
                        if (d < TDIM_) tv = fast_cos(dt[bb] * time_w[d]);
                        bf[bb][i] = nz[bb] ? (_Float16)0.f : (_Float16)tv;
                    }
                }
            }
#pragma unroll
            for (int nt = 0; nt < 4; ++nt) {
                pacc[0][nt] = __builtin_amdgcn_mfma_f32_16x16x32_f16(af[nt], bf[0], pacc[0][nt], 0, 0, 0);
                pacc[1][nt] = __builtin_amdgcn_mfma_f32_16x16x32_f16(af[nt], bf[1], pacc[1][nt], 0, 0, 0);
            }
        }
#pragma unroll
        for (int bb = 0; bb < 2; ++bb)
#pragma unroll
            for (int nt = 0; nt < 4; ++nt) {
                f16x4 st;
#pragma unroll
                for (int j = 0; j < 4; ++j) st[j] = (_Float16)pacc[bb][nt][j];
                *(f16x4*)&xf[bb][row16 * 72 + 16 * nt + 4 * g] = st;
            }
    }
    __syncthreads();

    // ================= mixer layers =================
    for (int l = 0; l < L_; ++l) {
        // ---- token LN (over k, per c), both b ----
#pragma unroll
        for (int bb = 0; bb < 2; ++bb) {
            const int c0 = row16;
            float xv[16], s = 0.f, ss = 0.f;
#pragma unroll
            for (int u = 0; u < 16; ++u) {
                const float v = (float)xf[bb][(16 * g + u) * 72 + c0];
                xv[u] = v; s += v; ss += v * v;
            }
            s += __shfl_xor(s, 16); ss += __shfl_xor(ss, 16);
            s += __shfl_xor(s, 32); ss += __shfl_xor(ss, 32);
            const float mean = s * 0.015625f;
            const float rstd = rsqrtf(ss * 0.015625f - mean * mean + 1e-5f);
            const float* tls = tok_ln_s + l * 64 + 16 * g;
            const float* tlb = tok_ln_b + l * 64 + 16 * g;
            f16x8 h0, h1;
#pragma unroll
            for (int u = 0; u < 8; ++u)
                h0[u] = (_Float16)((xv[u] - mean) * rstd * tls[u] + tlb[u]);
#pragma unroll
            for (int u = 0; u < 8; ++u)
                h1[u] = (_Float16)((xv[8 + u] - mean) * rstd * tls[8 + u] + tlb[8 + u]);
            *(f16x8*)&sh[bb][c0 * 72 + 16 * g]     = h0;   // xh^T[c][k]
            *(f16x8*)&sh[bb][c0 * 72 + 16 * g + 8] = h1;
        }
        // ---- token G1 + G2 + residual (weight frags shared across b) ----
        {
            const _Float16* W1 = pT1 + l * 2048;   // [j][k]
            const _Float16* W2 = pT2 + l * 2048;   // [k][j]
            f16x8 tb0[2], tb1[2];
#pragma unroll
            for (int bb = 0; bb < 2; ++bb) {
                tb0[bb] = *(const f16x8*)&sh[bb][row16 * 72 + 8 * g];
                tb1[bb] = *(const f16x8*)&sh[bb][row16 * 72 + 32 + 8 * g];
            }
#pragma unroll
            for (int nt = 0; nt < 2; ++nt) {
                const f16x8 a0 = *(const f16x8*)&W1[(16 * nt + r) * 64 + 8 * g];
                const f16x8 a1 = *(const f16x8*)&W1[(16 * nt + r) * 64 + 32 + 8 * g];
                const f32x4 bias = *(const f32x4*)&tok_b1[l * 32 + 16 * nt + 4 * g];
#pragma unroll
                for (int bb = 0; bb < 2; ++bb) {
                    f32x4 acc = bias;
                    acc = __builtin_amdgcn_mfma_f32_16x16x32_f16(a0, tb0[bb], acc, 0, 0, 0);
                    acc = __builtin_amdgcn_mfma_f32_16x16x32_f16(a1, tb1[bb], acc, 0, 0, 0);
                    f16x4 hq;
#pragma unroll
                    for (int jj = 0; jj < 4; ++jj) hq[jj] = (_Float16)gelu_f(acc[jj]);
                    *(f16x4*)&sh[bb][row16 * 72 + 16 * nt + 4 * g] = hq;   // hb cols 0..31
                }
            }
            f16x8 a[2];
#pragma unroll
            for (int bb = 0; bb < 2; ++bb)
                a[bb] = *(const f16x8*)&sh[bb][row16 * 72 + 8 * g];   // H: c=row16
#pragma unroll
            for (int nt = 0; nt < 4; ++nt) {
                const int kcol = 16 * nt + r;
                const float bk = tok_b2[l * 64 + kcol];
                const f16x8 bf = *(const f16x8*)&W2[kcol * 32 + 8 * g];
#pragma unroll
                for (int bb = 0; bb < 2; ++bb) {
                    f32x4 acc = {bk, bk, bk, bk};
                    acc = __builtin_amdgcn_mfma_f32_16x16x32_f16(a[bb], bf, acc, 0, 0, 0);
                    rmw16(&xf[bb][kcol * 72 + 16 * w + 4 * g], acc);   // own c-slice
                }
            }
        }
        __syncthreads();   // token residual visible before channel LN

        // ---- channel LN (over c, per k), both b ----
#pragma unroll
        for (int bb = 0; bb < 2; ++bb) {
            const int k0 = row16;
            const f16x8 cva = *(const f16x8*)&xf[bb][k0 * 72 + 16 * g];
            const f16x8 cvb = *(const f16x8*)&xf[bb][k0 * 72 + 16 * g + 8];
            float cv[16], s = 0.f, ss = 0.f;
#pragma unroll
            for (int e = 0; e < 8; ++e) { cv[e] = (float)cva[e]; cv[8 + e] = (float)cvb[e]; }
#pragma unroll
            for (int e = 0; e < 16; ++e) { s += cv[e]; ss += cv[e] * cv[e]; }
            s += __shfl_xor(s, 16); ss += __shfl_xor(ss, 16);
            s += __shfl_xor(s, 32); ss += __shfl_xor(ss, 32);
            const float mean = s * 0.015625f;
            const float rstd = rsqrtf(ss * 0.015625f - mean * mean + 1e-5f);
            const float* cls = ch_ln_s + l * 64 + 16 * g;
            const float* clb = ch_ln_b + l * 64 + 16 * g;
            f16x8 h0, h1;
#pragma unroll
            for (int e = 0; e < 8; ++e) {
                h0[e] = (_Float16)((cv[e] - mean) * rstd * cls[e] + clb[e]);
                h1[e] = (_Float16)((cv[8 + e] - mean) * rstd * cls[8 + e] + clb[8 + e]);
            }
            *(f16x8*)&sh[bb][k0 * 72 + 16 * g]     = h0;   // xh[k][c]
            *(f16x8*)&sh[bb][k0 * 72 + 16 * g + 8] = h1;
        }
        // ---- channel MLP (shared Wc1/Wc2 frags; q unrolled) ----
        {
            f16x8 ca0[2], ca1[2];
#pragma unroll
            for (int bb = 0; bb < 2; ++bb) {
                ca0[bb] = *(const f16x8*)&sh[bb][row16 * 72 + 8 * g];
                ca1[bb] = *(const f16x8*)&sh[bb][row16 * 72 + 32 + 8 * g];
            }
            const _Float16* Wc1 = pC1 + l * 16384;   // [n][c]
            const _Float16* Wc2 = pC2 + l * 16384;   // [c][n]
            f32x4 cacc[2][4];
#pragma unroll
            for (int nt = 0; nt < 4; ++nt) {
                const f32x4 cb = *(const f32x4*)&ch_b2[l * 64 + 16 * nt + 4 * g];
                cacc[0][nt] = cb; cacc[1][nt] = cb;
            }
#pragma unroll
            for (int q = 0; q < 4; ++q) {
#pragma unroll
                for (int nt = 0; nt < 4; ++nt) {
                    const int nrow = 64 * q + 16 * nt + r;
                    const f16x8 a0 = *(const f16x8*)&Wc1[nrow * 64 + 8 * g];
                    const f16x8 a1 = *(const f16x8*)&Wc1[nrow * 64 + 32 + 8 * g];
                    const f32x4 hb1 = *(const f32x4*)&ch_b1[l * 256 + 64 * q + 16 * nt + 4 * g];
#pragma unroll
                    for (int bb = 0; bb < 2; ++bb) {
                        f32x4 acc = hb1;
                        acc = __builtin_amdgcn_mfma_f32_16x16x32_f16(a0, ca0[bb], acc, 0, 0, 0);
                        acc = __builtin_amdgcn_mfma_f32_16x16x32_f16(a1, ca1[bb], acc, 0, 0, 0);
                        f16x4 hq;
#pragma unroll
                        for (int jj = 0; jj < 4; ++jj) hq[jj] = (_Float16)gelu_f(acc[jj]);
                        *(f16x4*)&sh[bb][row16 * 72 + 16 * nt + 4 * g] = hq;   // H cols 0..63
                    }
                }
#pragma unroll
                for (int ks = 0; ks < 2; ++ks) {
                    f16x8 bh[2];
#pragma unroll
                    for (int bb = 0; bb < 2; ++bb)
                        bh[bb] = *(const f16x8*)&sh[bb][row16 * 72 + 32 * ks + 8 * g];
#pragma unroll
                    for (int nt2 = 0; nt2 < 4; ++nt2) {
                        const f16x8 a2 = *(const f16x8*)&Wc2[(16 * nt2 + r) * 256 + 64 * q + 32 * ks + 8 * g];
                        cacc[0][nt2] = __builtin_amdgcn_mfma_f32_16x16x32_f16(a2, bh[0], cacc[0][nt2], 0, 0, 0);
                        cacc[1][nt2] = __builtin_amdgcn_mfma_f32_16x16x32_f16(a2, bh[1], cacc[1][nt2], 0, 0, 0);
                    }
                }
            }
#pragma unroll
            for (int bb = 0; bb < 2; ++bb)
#pragma unroll
                for (int nt2 = 0; nt2 < 4; ++nt2)
                    rmw16(&xf[bb][row16 * 72 + 16 * nt2 + 4 * g], cacc[bb][nt2]);
        }
        __syncthreads();   // layer complete
    }

    // ---- agg: mean over k per c, both b ----
#pragma unroll
    for (int bb = 0; bb < 2; ++bb) {
        float ssum = 0.f;
#pragma unroll
        for (int u = 0; u < 16; ++u) ssum += (float)xf[bb][(16 * g + u) * 72 + row16];
        ssum += __shfl_xor(ssum, 16);
        ssum += __shfl_xor(ssum, 32);
        if (g == 0) agg_out[(size_t)(2 * bid + bb) * 64 + row16] = ssum * 0.015625f;
    }
}

// ---------------------------------------------------------------------------
// Kernel 3 (round-13 verified): 16 batch rows per block, 512 threads. Gap
// gather split into two 50-id halves per b to halve the serial latency chain;
// partials combined via LDS. MFMA GEMV over 8 waves.
// ---------------------------------------------------------------------------
__global__ __launch_bounds__(512)
void out_kernel(const float* __restrict__ node_table,
                const float* __restrict__ agg,
                const _Float16* __restrict__ pOW,
                const float* __restrict__ out_b,
                const int*   __restrict__ node_ids,
                const int*   __restrict__ gap_ids,
                float* __restrict__ out) {
    __shared__ __attribute__((aligned(16))) _Float16 inb16[16][264];
    __shared__ float part[16][176];
    __shared__ int   nv1[16];
    const int t     = threadIdx.x;
    const int bbase = blockIdx.x * 16;
    const int m     = t >> 5;          // local b row 0..15
    const int sub   = (t >> 4) & 1;    // id-half
    const int c16   = t & 15;
    const int b     = bbase + m;

    if (sub == 0) {
#pragma unroll
        for (int j = 0; j < 4; ++j)
            inb16[m][c16 + 16 * j] = (_Float16)agg[(size_t)b * C_ + c16 + 16 * j];
        inb16[m][236 + c16] = (_Float16)0.f;            // 236..251
        if (c16 < 12) inb16[m][252 + c16] = (_Float16)0.f;  // 252..263
    }
    // gather: this sub's 50 ids
    float acc[11];
#pragma unroll
    for (int j = 0; j < 11; ++j) acc[j] = 0.f;
    int nv = 0;
    {
        const int* gid = gap_ids + (size_t)b * G_ + 50 * sub;
        for (int gg = 0; gg < 50; ++gg) {
            const int id = gid[gg];
            if (id > 0) {
                ++nv;
                const float* row = node_table + (size_t)id * FEAT_;
#pragma unroll
                for (int j = 0; j < 11; ++j) {
                    const int c = c16 + 16 * j;
                    if (c < FEAT_) acc[j] += row[c];
                }
            }
        }
    }
    if (sub == 1) {
#pragma unroll
        for (int j = 0; j < 11; ++j) {
            const int c = c16 + 16 * j;
            if (c < FEAT_) part[m][c] = acc[j];
        }
        if (c16 == 0) nv1[m] = nv;
    }
    __syncthreads();
    if (sub == 0) {
        const int nvt = nv + nv1[m];
        const float scale = 1.0f / (float)(G_ * (nvt > 0 ? nvt : 1));
        const float* nrow = node_table + (size_t)node_ids[b] * FEAT_;
#pragma unroll
        for (int j = 0; j < 11; ++j) {
            const int c = c16 + 16 * j;
            if (c < FEAT_)
                inb16[m][64 + c] = (_Float16)(fmaf(acc[j] + part[m][c], scale, nrow[c]));
        }
    }
    __syncthreads();

    // MFMA GEMV: 11 n-tiles over 8 waves
    const int lane = t & 63;
    const int w = t >> 6;
    const int r = lane & 15;
    const int g = lane >> 4;
    f16x8 bf[8];
#pragma unroll
    for (int kk = 0; kk < 8; ++kk)
        bf[kk] = *(const f16x8*)&inb16[r][32 * kk + 8 * g];
    for (int nt = w; nt < 11; nt += 8) {
        const int n0 = nt * 16 + 4 * g;
        const int bidx = (n0 + 4 <= FEAT_) ? n0 : (FEAT_ - 4);
        f32x4 acc = *(const f32x4*)&out_b[bidx];
#pragma unroll
        for (int kk = 0; kk < 8; ++kk) {
            const f16x8 af = *(const f16x8*)&pOW[(nt * 16 + r) * 256 + 32 * kk + 8 * g];
            acc = __builtin_amdgcn_mfma_f32_16x16x32_f16(af, bf[kk], acc, 0, 0, 0);
        }
        if (n0 + 4 <= FEAT_)
            *(f32x4*)&out[(size_t)(bbase + r) * FEAT_ + n0] = acc;
    }
}

// ---------------------------------------------------------------------------
extern "C" void kernel_launch(void* const* d_in, const int* in_sizes, int n_in,
                              void* d_out, int out_size, void* d_ws, size_t ws_size,
                              hipStream_t stream) {
    const float* node_table = (const float*)d_in[0];
    const float* edge_table = (const float*)d_in[1];
    const float* time_w     = (const float*)d_in[2];
    const float* proj_W     = (const float*)d_in[3];
    const float* proj_b     = (const float*)d_in[4];
    const float* tok_ln_s   = (const float*)d_in[5];
    const float* tok_ln_b   = (const float*)d_in[6];
    const float* tok_W1     = (const float*)d_in[7];
    const float* tok_b1     = (const float*)d_in[8];
    const float* tok_W2     = (const float*)d_in[9];
    const float* tok_b2     = (const float*)d_in[10];
    const float* ch_ln_s    = (const float*)d_in[11];
    const float* ch_ln_b    = (const float*)d_in[12];
    const float* ch_W1      = (const float*)d_in[13];
    const float* ch_b1      = (const float*)d_in[14];
    const float* ch_W2      = (const float*)d_in[15];
    const float* ch_b2      = (const float*)d_in[16];
    const float* out_W      = (const float*)d_in[17];
    const float* out_b      = (const float*)d_in[18];
    const int*   node_ids   = (const int*)d_in[19];
    const int*   nbr_nids   = (const int*)d_in[20];
    const int*   nbr_eids   = (const int*)d_in[21];
    const int*   gap_ids    = (const int*)d_in[22];
    const float* node_times = (const float*)d_in[23];
    const float* nbr_times  = (const float*)d_in[24];

    float* agg_buf = (float*)d_ws;                       // B*C f32 = 2 MiB
    _Float16* pw   = (_Float16*)(agg_buf + (size_t)B_ * C_);
    _Float16* pW   = pw;               // 64*288   = 18432
    _Float16* pT1  = pW  + 18432;      // 2*32*64  = 4096
    _Float16* pT2  = pT1 + 4096;       // 2*64*32  = 4096
    _Float16* pC1  = pT2 + 4096;       // 2*256*64 = 32768
    _Float16* pC2  = pC1 + 32768;      // 2*64*256 = 32768
    _Float16* pOW  = pC2 + 32768;      // 176*256  = 45056
    float* outp    = (float*)d_out;

    prepack_kernel<<<64, 256, 0, stream>>>(proj_W, tok_W1, tok_W2, ch_W1, ch_W2,
                                           out_W, pW, pT1, pT2, pC1, pC2, pOW);
    fused_kernel<<<B_ / 2, 256, 0, stream>>>(edge_table, time_w, pW, proj_b,
                                             nbr_nids, nbr_eids, node_times, nbr_times,
                                             tok_ln_s, tok_ln_b, tok_b1, tok_b2,
                                             ch_ln_s, ch_ln_b, ch_b1, ch_b2,
                                             pT1, pT2, pC1, pC2,
                                             agg_buf);
    out_kernel<<<B_ / 16, 512, 0, stream>>>(node_table, agg_buf, pOW, out_b,
                                            node_ids, gap_ids, outp);
}

// Round 15
// 466.002 us; speedup vs baseline: 1.2452x; 1.0944x over previous
//
#include <hip/hip_runtime.h>
#include <math.h>

#define B_    8192
#define K_    64
#define C_    64
#define FEAT_ 172
#define TDIM_ 100
#define TOKH_ 32
#define CHH_  256
#define G_    100
#define L_    2
#define CAT_  236      // C_+FEAT_
#define NB_   4        // batch elements per block (r7: 1->2 = 1.45x; now 2->4)

typedef _Float16 f16x8 __attribute__((ext_vector_type(8)));
typedef _Float16 f16x4 __attribute__((ext_vector_type(4)));
typedef float    f32x4 __attribute__((ext_vector_type(4)));

// Fast exact-range cos: f32 product (same rounding as the jax ref), f64 range
// reduction (exact for |p|<=2e6), hardware v_cos (takes revolutions).
__device__ __forceinline__ float fast_cos(float p) {
    const double rev = (double)p * 0.15915494309189535;   // p / 2pi
    const double fr  = rev - __builtin_rint(rev);         // [-0.5, 0.5]
#if __has_builtin(__builtin_amdgcn_cosf)
    return __builtin_amdgcn_cosf((float)fr);
#else
    return __cosf(6.283185307179586f * (float)fr);
#endif
}

// GELU via A&S 7.1.25 erf (|err|<2.5e-5), v_rcp instead of fdiv: ~13 VALU.
__device__ __forceinline__ float gelu_f(float x) {
    const float z  = x * 0.70710678118654752f;
    const float az = fabsf(z);
    const float t  = __builtin_amdgcn_rcpf(fmaf(0.47047f, az, 1.0f));
    const float poly = t * (0.3480242f + t * (-0.0958798f + t * 0.7478556f));
    const float e  = __expf(-az * az);
    float erfv = fmaf(-poly, e, 1.0f);
    erfv = copysignf(erfv, z);
    return 0.5f * x * (1.0f + erfv);
}

// f16 state RMW: p += add (f32 math, f16 storage)
__device__ __forceinline__ void rmw16(_Float16* p, f32x4 add) {
    const f16x4 old = *(const f16x4*)p;
    f16x4 nw;
#pragma unroll
    for (int j = 0; j < 4; ++j) nw[j] = (_Float16)((float)old[j] + add[j]);
    *(f16x4*)p = nw;
}

// ---------------------------------------------------------------------------
// Prepack weights to f16. pW (64 x 288): cols 0..171 edge, 176..275 time.
// pOW (176 x 256): pOW[n][k] = out_W[k][n], zero-padded.
// ---------------------------------------------------------------------------
__global__ __launch_bounds__(256)
void prepack_kernel(const float* __restrict__ proj_W,
                    const float* __restrict__ tW1, const float* __restrict__ tW2,
                    const float* __restrict__ cW1, const float* __restrict__ cW2,
                    const float* __restrict__ out_W,
                    _Float16* __restrict__ pW,
                    _Float16* __restrict__ pT1, _Float16* __restrict__ pT2,
                    _Float16* __restrict__ pC1, _Float16* __restrict__ pC2,
                    _Float16* __restrict__ pOW) {
    const int stride = gridDim.x * blockDim.x;
    const int t0 = blockIdx.x * blockDim.x + threadIdx.x;
    for (int i = t0; i < 64 * 288; i += stride) {
        const int c = i / 288, ii = i % 288;
        float v = 0.f;
        if (ii < 172) v = proj_W[ii * 64 + c];
        else if (ii >= 176 && ii < 276) v = proj_W[(ii - 4) * 64 + c];
        pW[i] = (_Float16)v;
    }
    for (int i = t0; i < 2 * 32 * 64; i += stride) {           // pT1[l][j][k]
        const int l = i / 2048, rem = i % 2048, j = rem / 64, k = rem % 64;
        pT1[i] = (_Float16)tW1[l * 2048 + k * 32 + j];
    }
    for (int i = t0; i < 2 * 64 * 32; i += stride) {           // pT2[l][k][j]
        const int l = i / 2048, rem = i % 2048, k = rem / 32, j = rem % 32;
        pT2[i] = (_Float16)tW2[l * 2048 + j * 64 + k];
    }
    for (int i = t0; i < 2 * 256 * 64; i += stride) {          // pC1[l][n][c]
        const int l = i / 16384, rem = i % 16384, n = rem / 64, c = rem % 64;
        pC1[i] = (_Float16)cW1[l * 16384 + c * 256 + n];
    }
    for (int i = t0; i < 2 * 64 * 256; i += stride) {          // pC2[l][c][n]
        const int l = i / 16384, rem = i % 16384, c = rem / 256, n = rem % 256;
        pC2[i] = (_Float16)cW2[l * 16384 + n * 64 + c];
    }
    for (int i = t0; i < 176 * 256; i += stride) {             // pOW[n][k]
        const int n = i / 256, k = i % 256;
        pOW[i] = (n < FEAT_ && k < CAT_) ? (_Float16)out_W[k * FEAT_ + n]
                                         : (_Float16)0.f;
    }
}

// ---------------------------------------------------------------------------
// Fused kernel, FOUR batch elements/block. Structure identical to the
// verified r14 kernel (f16 xf, per-b sh, shared weight frags) with bb
// widened 2->4: each weight fragment feeds 4 MFMAs (weight traffic
// 3 GB -> 1.5 GB) and each wave carries 4 independent chains.
// LDS 73.7 KB -> 2 blocks/CU; (256,2) so no VGPR cap pressure.
// Frag maps (HW-verified): A/B: lane l -> row/col l&15, kelem 8*(l>>4)+i;
// D: col l&15, row 4*(l>>4)+jj.
// ---------------------------------------------------------------------------
__global__ __launch_bounds__(256, 2)
void fused_kernel(const float* __restrict__ edge_table,
                  const float* __restrict__ time_w,
                  const _Float16* __restrict__ pW,
                  const float* __restrict__ proj_b,
                  const int*   __restrict__ nbr_nids,
                  const int*   __restrict__ nbr_eids,
                  const float* __restrict__ node_times,
                  const float* __restrict__ nbr_times,
                  const float* __restrict__ tok_ln_s, const float* __restrict__ tok_ln_b,
                  const float* __restrict__ tok_b1,   const float* __restrict__ tok_b2,
                  const float* __restrict__ ch_ln_s,  const float* __restrict__ ch_ln_b,
                  const float* __restrict__ ch_b1,    const float* __restrict__ ch_b2,
                  const _Float16* __restrict__ pT1, const _Float16* __restrict__ pT2,
                  const _Float16* __restrict__ pC1, const _Float16* __restrict__ pC2,
                  float* __restrict__ agg_out) {
    __shared__ __attribute__((aligned(16))) _Float16 xf[NB_][64 * 72];  // 36864 B
    __shared__ __attribute__((aligned(16))) _Float16 sh[NB_][64 * 72];  // 36864 B

    const int bid  = blockIdx.x;
    const int t    = threadIdx.x;
    const int lane = t & 63;
    const int w    = t >> 6;
    const int r    = lane & 15;
    const int g    = lane >> 4;
    const int row16 = 16 * w + r;

    // ================= proj phase =================
    {
        const float* erow[NB_];
        bool  nz[NB_];
        float dt[NB_];
#pragma unroll
        for (int bb = 0; bb < NB_; ++bb) {
            const size_t bgl = (size_t)(NB_ * bid + bb) * K_ + row16;
            erow[bb] = edge_table + (size_t)nbr_eids[bgl] * FEAT_;
            nz[bb]   = (nbr_nids[bgl] == 0);
            dt[bb]   = node_times[NB_ * bid + bb] - nbr_times[bgl];
        }

        f32x4 pacc[NB_][4];
#pragma unroll
        for (int nt = 0; nt < 4; ++nt) {
            const f32x4 pb = *(const f32x4*)&proj_b[16 * nt + 4 * g];
#pragma unroll
            for (int bb = 0; bb < NB_; ++bb) pacc[bb][nt] = pb;
        }

        const int c0b = 8 * g;
#pragma unroll
        for (int kk = 0; kk < 9; ++kk) {
            const int c0 = 32 * kk + c0b;
            f16x8 af[4];
#pragma unroll
            for (int nt = 0; nt < 4; ++nt)
                af[nt] = *(const f16x8*)&pW[(16 * nt + r) * 288 + c0];
#pragma unroll
            for (int bb = 0; bb < NB_; ++bb) {
                f16x8 bf;
                if (c0 + 8 <= FEAT_) {
                    const float4 v0 = *(const float4*)(erow[bb] + c0);
                    const float4 v1 = *(const float4*)(erow[bb] + c0 + 4);
                    bf[0]=(_Float16)v0.x; bf[1]=(_Float16)v0.y;
                    bf[2]=(_Float16)v0.z; bf[3]=(_Float16)v0.w;
                    bf[4]=(_Float16)v1.x; bf[5]=(_Float16)v1.y;
                    bf[6]=(_Float16)v1.z; bf[7]=(_Float16)v1.w;
                } else if (c0 < 176) {       // c0==168: edge 168..171 + pad
                    const float4 v0 = *(const float4*)(erow[bb] + 168);
                    bf[0]=(_Float16)v0.x; bf[1]=(_Float16)v0.y;
                    bf[2]=(_Float16)v0.z; bf[3]=(_Float16)v0.w;
                    bf[4]=(_Float16)0.f; bf[5]=(_Float16)0.f;
                    bf[6]=(_Float16)0.f; bf[7]=(_Float16)0.f;
                } else {                     // time cols
                    const int d0 = c0 - 176;
#pragma unroll
                    for (int i = 0; i < 8; ++i) {
                        const int d = d0 + i;
                        float tv = 0.f;
                        if (d < TDIM_) tv = fast_cos(dt[bb] * time_w[d]);
                        bf[i] = nz[bb] ? (_Float16)0.f : (_Float16)tv;
                    }
                }
#pragma unroll
                for (int nt = 0; nt < 4; ++nt)
                    pacc[bb][nt] = __builtin_amdgcn_mfma_f32_16x16x32_f16(af[nt], bf, pacc[bb][nt], 0, 0, 0);
            }
        }
#pragma unroll
        for (int bb = 0; bb < NB_; ++bb)
#pragma unroll
            for (int nt = 0; nt < 4; ++nt) {
                f16x4 st;
#pragma unroll
                for (int j = 0; j < 4; ++j) st[j] = (_Float16)pacc[bb][nt][j];
                *(f16x4*)&xf[bb][row16 * 72 + 16 * nt + 4 * g] = st;
            }
    }
    __syncthreads();

    // ================= mixer layers =================
    for (int l = 0; l < L_; ++l) {
        // ---- token LN (over k, per c), all b ----
#pragma unroll
        for (int bb = 0; bb < NB_; ++bb) {
            const int c0 = row16;
            float xv[16], s = 0.f, ss = 0.f;
#pragma unroll
            for (int u = 0; u < 16; ++u) {
                const float v = (float)xf[bb][(16 * g + u) * 72 + c0];
                xv[u] = v; s += v; ss += v * v;
            }
            s += __shfl_xor(s, 16); ss += __shfl_xor(ss, 16);
            s += __shfl_xor(s, 32); ss += __shfl_xor(ss, 32);
            const float mean = s * 0.015625f;
            const float rstd = rsqrtf(ss * 0.015625f - mean * mean + 1e-5f);
            const float* tls = tok_ln_s + l * 64 + 16 * g;
            const float* tlb = tok_ln_b + l * 64 + 16 * g;
            f16x8 h0, h1;
#pragma unroll
            for (int u = 0; u < 8; ++u)
                h0[u] = (_Float16)((xv[u] - mean) * rstd * tls[u] + tlb[u]);
#pragma unroll
            for (int u = 0; u < 8; ++u)
                h1[u] = (_Float16)((xv[8 + u] - mean) * rstd * tls[8 + u] + tlb[8 + u]);
            *(f16x8*)&sh[bb][c0 * 72 + 16 * g]     = h0;   // xh^T[c][k]
            *(f16x8*)&sh[bb][c0 * 72 + 16 * g + 8] = h1;
        }
        // ---- token G1 + G2 + residual (weight frags shared across b) ----
        {
            const _Float16* W1 = pT1 + l * 2048;   // [j][k]
            const _Float16* W2 = pT2 + l * 2048;   // [k][j]
            f16x8 tb0[NB_], tb1[NB_];
#pragma unroll
            for (int bb = 0; bb < NB_; ++bb) {
                tb0[bb] = *(const f16x8*)&sh[bb][row16 * 72 + 8 * g];
                tb1[bb] = *(const f16x8*)&sh[bb][row16 * 72 + 32 + 8 * g];
            }
#pragma unroll
            for (int nt = 0; nt < 2; ++nt) {
                const f16x8 a0 = *(const f16x8*)&W1[(16 * nt + r) * 64 + 8 * g];
                const f16x8 a1 = *(const f16x8*)&W1[(16 * nt + r) * 64 + 32 + 8 * g];
                const f32x4 bias = *(const f32x4*)&tok_b1[l * 32 + 16 * nt + 4 * g];
#pragma unroll
                for (int bb = 0; bb < NB_; ++bb) {
                    f32x4 acc = bias;
                    acc = __builtin_amdgcn_mfma_f32_16x16x32_f16(a0, tb0[bb], acc, 0, 0, 0);
                    acc = __builtin_amdgcn_mfma_f32_16x16x32_f16(a1, tb1[bb], acc, 0, 0, 0);
                    f16x4 hq;
#pragma unroll
                    for (int jj = 0; jj < 4; ++jj) hq[jj] = (_Float16)gelu_f(acc[jj]);
                    *(f16x4*)&sh[bb][row16 * 72 + 16 * nt + 4 * g] = hq;   // hb cols 0..31
                }
            }
            f16x8 a[NB_];
#pragma unroll
            for (int bb = 0; bb < NB_; ++bb)
                a[bb] = *(const f16x8*)&sh[bb][row16 * 72 + 8 * g];   // H: c=row16
#pragma unroll
            for (int nt = 0; nt < 4; ++nt) {
                const int kcol = 16 * nt + r;
                const float bk = tok_b2[l * 64 + kcol];
                const f16x8 bf = *(const f16x8*)&W2[kcol * 32 + 8 * g];
#pragma unroll
                for (int bb = 0; bb < NB_; ++bb) {
                    f32x4 acc = {bk, bk, bk, bk};
                    acc = __builtin_amdgcn_mfma_f32_16x16x32_f16(a[bb], bf, acc, 0, 0, 0);
                    rmw16(&xf[bb][kcol * 72 + 16 * w + 4 * g], acc);   // own c-slice
                }
            }
        }
        __syncthreads();   // token residual visible before channel LN

        // ---- channel LN (over c, per k), all b ----
#pragma unroll
        for (int bb = 0; bb < NB_; ++bb) {
            const int k0 = row16;
            const f16x8 cva = *(const f16x8*)&xf[bb][k0 * 72 + 16 * g];
            const f16x8 cvb = *(const f16x8*)&xf[bb][k0 * 72 + 16 * g + 8];
            float cv[16], s = 0.f, ss = 0.f;
#pragma unroll
            for (int e = 0; e < 8; ++e) { cv[e] = (float)cva[e]; cv[8 + e] = (float)cvb[e]; }
#pragma unroll
            for (int e = 0; e < 16; ++e) { s += cv[e]; ss += cv[e] * cv[e]; }
            s += __shfl_xor(s, 16); ss += __shfl_xor(ss, 16);
            s += __shfl_xor(s, 32); ss += __shfl_xor(ss, 32);
            const float mean = s * 0.015625f;
            const float rstd = rsqrtf(ss * 0.015625f - mean * mean + 1e-5f);
            const float* cls = ch_ln_s + l * 64 + 16 * g;
            const float* clb = ch_ln_b + l * 64 + 16 * g;
            f16x8 h0, h1;
#pragma unroll
            for (int e = 0; e < 8; ++e) {
                h0[e] = (_Float16)((cv[e] - mean) * rstd * cls[e] + clb[e]);
                h1[e] = (_Float16)((cv[8 + e] - mean) * rstd * cls[8 + e] + clb[8 + e]);
            }
            *(f16x8*)&sh[bb][k0 * 72 + 16 * g]     = h0;   // xh[k][c]
            *(f16x8*)&sh[bb][k0 * 72 + 16 * g + 8] = h1;
        }
        // ---- channel MLP (shared Wc1/Wc2 frags; q loop NOT unrolled to
        //      keep register pressure in check at NB_=4) ----
        {
            f16x8 ca0[NB_], ca1[NB_];
#pragma unroll
            for (int bb = 0; bb < NB_; ++bb) {
                ca0[bb] = *(const f16x8*)&sh[bb][row16 * 72 + 8 * g];
                ca1[bb] = *(const f16x8*)&sh[bb][row16 * 72 + 32 + 8 * g];
            }
            const _Float16* Wc1 = pC1 + l * 16384;   // [n][c]
            const _Float16* Wc2 = pC2 + l * 16384;   // [c][n]
            f32x4 cacc[NB_][4];
#pragma unroll
            for (int nt = 0; nt < 4; ++nt) {
                const f32x4 cb = *(const f32x4*)&ch_b2[l * 64 + 16 * nt + 4 * g];
#pragma unroll
                for (int bb = 0; bb < NB_; ++bb) cacc[bb][nt] = cb;
            }
            for (int q = 0; q < 4; ++q) {
#pragma unroll
                for (int nt = 0; nt < 4; ++nt) {
                    const int nrow = 64 * q + 16 * nt + r;
                    const f16x8 a0 = *(const f16x8*)&Wc1[nrow * 64 + 8 * g];
                    const f16x8 a1 = *(const f16x8*)&Wc1[nrow * 64 + 32 + 8 * g];
                    const f32x4 hb1 = *(const f32x4*)&ch_b1[l * 256 + 64 * q + 16 * nt + 4 * g];
#pragma unroll
                    for (int bb = 0; bb < NB_; ++bb) {
                        f32x4 acc = hb1;
                        acc = __builtin_amdgcn_mfma_f32_16x16x32_f16(a0, ca0[bb], acc, 0, 0, 0);
                        acc = __builtin_amdgcn_mfma_f32_16x16x32_f16(a1, ca1[bb], acc, 0, 0, 0);
                        f16x4 hq;
#pragma unroll
                        for (int jj = 0; jj < 4; ++jj) hq[jj] = (_Float16)gelu_f(acc[jj]);
                        *(f16x4*)&sh[bb][row16 * 72 + 16 * nt + 4 * g] = hq;   // H cols 0..63
                    }
                }
#pragma unroll
                for (int ks = 0; ks < 2; ++ks) {
#pragma unroll
                    for (int nt2 = 0; nt2 < 4; ++nt2) {
                        const f16x8 a2 = *(const f16x8*)&Wc2[(16 * nt2 + r) * 256 + 64 * q + 32 * ks + 8 * g];
#pragma unroll
                        for (int bb = 0; bb < NB_; ++bb) {
                            const f16x8 bh = *(const f16x8*)&sh[bb][row16 * 72 + 32 * ks + 8 * g];
                            cacc[bb][nt2] = __builtin_amdgcn_mfma_f32_16x16x32_f16(a2, bh, cacc[bb][nt2], 0, 0, 0);
                        }
                    }
                }
            }
#pragma unroll
            for (int bb = 0; bb < NB_; ++bb)
#pragma unroll
                for (int nt2 = 0; nt2 < 4; ++nt2)
                    rmw16(&xf[bb][row16 * 72 + 16 * nt2 + 4 * g], cacc[bb][nt2]);
        }
        __syncthreads();   // layer complete
    }

    // ---- agg: mean over k per c, all b ----
#pragma unroll
    for (int bb = 0; bb < NB_; ++bb) {
        float ssum = 0.f;
#pragma unroll
        for (int u = 0; u < 16; ++u) ssum += (float)xf[bb][(16 * g + u) * 72 + row16];
        ssum += __shfl_xor(ssum, 16);
        ssum += __shfl_xor(ssum, 32);
        if (g == 0) agg_out[(size_t)(NB_ * bid + bb) * 64 + row16] = ssum * 0.015625f;
    }
}

// ---------------------------------------------------------------------------
// Kernel 3 (round-14 verified): 16 batch rows per block, 512 threads. Gap
// gather split into two 50-id halves per b; partials combined via LDS.
// MFMA GEMV over 8 waves.
// ---------------------------------------------------------------------------
__global__ __launch_bounds__(512)
void out_kernel(const float* __restrict__ node_table,
                const float* __restrict__ agg,
                const _Float16* __restrict__ pOW,
                const float* __restrict__ out_b,
                const int*   __restrict__ node_ids,
                const int*   __restrict__ gap_ids,
                float* __restrict__ out) {
    __shared__ __attribute__((aligned(16))) _Float16 inb16[16][264];
    __shared__ float part[16][176];
    __shared__ int   nv1[16];
    const int t     = threadIdx.x;
    const int bbase = blockIdx.x * 16;
    const int m     = t >> 5;          // local b row 0..15
    const int sub   = (t >> 4) & 1;    // id-half
    const int c16   = t & 15;
    const int b     = bbase + m;

    if (sub == 0) {
#pragma unroll
        for (int j = 0; j < 4; ++j)
            inb16[m][c16 + 16 * j] = (_Float16)agg[(size_t)b * C_ + c16 + 16 * j];
        inb16[m][236 + c16] = (_Float16)0.f;            // 236..251
        if (c16 < 12) inb16[m][252 + c16] = (_Float16)0.f;  // 252..263
    }
    // gather: this sub's 50 ids
    float acc[11];
#pragma unroll
    for (int j = 0; j < 11; ++j) acc[j] = 0.f;
    int nv = 0;
    {
        const int* gid = gap_ids + (size_t)b * G_ + 50 * sub;
        for (int gg = 0; gg < 50; ++gg) {
            const int id = gid[gg];
            if (id > 0) {
                ++nv;
                const float* row = node_table + (size_t)id * FEAT_;
#pragma unroll
                for (int j = 0; j < 11; ++j) {
                    const int c = c16 + 16 * j;
                    if (c < FEAT_) acc[j] += row[c];
                }
            }
        }
    }
    if (sub == 1) {
#pragma unroll
        for (int j = 0; j < 11; ++j) {
            const int c = c16 + 16 * j;
            if (c < FEAT_) part[m][c] = acc[j];
        }
        if (c16 == 0) nv1[m] = nv;
    }
    __syncthreads();
    if (sub == 0) {
        const int nvt = nv + nv1[m];
        const float scale = 1.0f / (float)(G_ * (nvt > 0 ? nvt : 1));
        const float* nrow = node_table + (size_t)node_ids[b] * FEAT_;
#pragma unroll
        for (int j = 0; j < 11; ++j) {
            const int c = c16 + 16 * j;
            if (c < FEAT_)
                inb16[m][64 + c] = (_Float16)(fmaf(acc[j] + part[m][c], scale, nrow[c]));
        }
    }
    __syncthreads();

    // MFMA GEMV: 11 n-tiles over 8 waves
    const int lane = t & 63;
    const int w = t >> 6;
    const int r = lane & 15;
    const int g = lane >> 4;
    f16x8 bf[8];
#pragma unroll
    for (int kk = 0; kk < 8; ++kk)
        bf[kk] = *(const f16x8*)&inb16[r][32 * kk + 8 * g];
    for (int nt = w; nt < 11; nt += 8) {
        const int n0 = nt * 16 + 4 * g;
        const int bidx = (n0 + 4 <= FEAT_) ? n0 : (FEAT_ - 4);
        f32x4 acc = *(const f32x4*)&out_b[bidx];
#pragma unroll
        for (int kk = 0; kk < 8; ++kk) {
            const f16x8 af = *(const f16x8*)&pOW[(nt * 16 + r) * 256 + 32 * kk + 8 * g];
            acc = __builtin_amdgcn_mfma_f32_16x16x32_f16(af, bf[kk], acc, 0, 0, 0);
        }
        if (n0 + 4 <= FEAT_)
            *(f32x4*)&out[(size_t)(bbase + r) * FEAT_ + n0] = acc;
    }
}

// ---------------------------------------------------------------------------
extern "C" void kernel_launch(void* const* d_in, const int* in_sizes, int n_in,
                              void* d_out, int out_size, void* d_ws, size_t ws_size,
                              hipStream_t stream) {
    const float* node_table = (const float*)d_in[0];
    const float* edge_table = (const float*)d_in[1];
    const float* time_w     = (const float*)d_in[2];
    const float* proj_W     = (const float*)d_in[3];
    const float* proj_b     = (const float*)d_in[4];
    const float* tok_ln_s   = (const float*)d_in[5];
    const float* tok_ln_b   = (const float*)d_in[6];
    const float* tok_W1     = (const float*)d_in[7];
    const float* tok_b1     = (const float*)d_in[8];
    const float* tok_W2     = (const float*)d_in[9];
    const float* tok_b2     = (const float*)d_in[10];
    const float* ch_ln_s    = (const float*)d_in[11];
    const float* ch_ln_b    = (const float*)d_in[12];
    const float* ch_W1      = (const float*)d_in[13];
    const float* ch_b1      = (const float*)d_in[14];
    const float* ch_W2      = (const float*)d_in[15];
    const float* ch_b2      = (const float*)d_in[16];
    const float* out_W      = (const float*)d_in[17];
    const float* out_b      = (const float*)d_in[18];
    const int*   node_ids   = (const int*)d_in[19];
    const int*   nbr_nids   = (const int*)d_in[20];
    const int*   nbr_eids   = (const int*)d_in[21];
    const int*   gap_ids    = (const int*)d_in[22];
    const float* node_times = (const float*)d_in[23];
    const float* nbr_times  = (const float*)d_in[24];

    float* agg_buf = (float*)d_ws;                       // B*C f32 = 2 MiB
    _Float16* pw   = (_Float16*)(agg_buf + (size_t)B_ * C_);
    _Float16* pW   = pw;               // 64*288   = 18432
    _Float16* pT1  = pW  + 18432;      // 2*32*64  = 4096
    _Float16* pT2  = pT1 + 4096;       // 2*64*32  = 4096
    _Float16* pC1  = pT2 + 4096;       // 2*256*64 = 32768
    _Float16* pC2  = pC1 + 32768;      // 2*64*256 = 32768
    _Float16* pOW  = pC2 + 32768;      // 176*256  = 45056
    float* outp    = (float*)d_out;

    prepack_kernel<<<64, 256, 0, stream>>>(proj_W, tok_W1, tok_W2, ch_W1, ch_W2,
                                           out_W, pW, pT1, pT2, pC1, pC2, pOW);
    fused_kernel<<<B_ / NB_, 256, 0, stream>>>(edge_table, time_w, pW, proj_b,
                                               nbr_nids, nbr_eids, node_times, nbr_times,
                                               tok_ln_s, tok_ln_b, tok_b1, tok_b2,
                                               ch_ln_s, ch_ln_b, ch_b1, ch_b2,
                                               pT1, pT2, pC1, pC2,
                                               agg_buf);
    out_kernel<<<B_ / 16, 512, 0, stream>>>(node_table, agg_buf, pOW, out_b,
                                            node_ids, gap_ids, outp);
}